// Round 1
// baseline (204.018 us; speedup 1.0000x reference)
//
#include <hip/hip_runtime.h>

typedef unsigned short ushort_t;
typedef unsigned int uint_t;
typedef __attribute__((ext_vector_type(4))) float f32x4;
typedef __attribute__((ext_vector_type(8))) short bf16x8;

#define B_   16
#define T_   2048
#define H_   1024
#define G_   2
#define V_   320
#define D_   128
#define NT   32768   // B*T
#define GV   640     // G*V
#define GD   256     // G*D

__device__ __forceinline__ ushort_t cvt_bf16(float f) {
  uint_t u = __float_as_uint(f);
  uint_t r = (u + 0x7FFFu + ((u >> 16) & 1u)) >> 16;
  return (ushort_t)r;
}

// ---------------- prep: convert weights to bf16, pack codebook frags, zero accums ----------------
__global__ void pq_prep(const float* __restrict__ W_in, const float* __restrict__ W_out,
                        const float* __restrict__ cb, ushort_t* __restrict__ winb,
                        ushort_t* __restrict__ woutb, ushort_t* __restrict__ cbp,
                        float* __restrict__ avg_g, float* __restrict__ closs) {
  int idx = blockIdx.x * 256 + threadIdx.x;
  const int N1 = GV * H_;    // 655360
  const int N2 = H_ * GD;    // 262144
  const int N3 = 81920;      // G * 10 * 8 * 64 * 8
  if (idx < N1) { winb[idx] = cvt_bf16(W_in[idx]); return; }
  idx -= N1;
  if (idx < N2) { woutb[idx] = cvt_bf16(W_out[idx]); return; }
  idx -= N2;
  if (idx < N3) {
    // cbp element e = (((g*10+kk)*8 + n)*64 + lane)*8 + i
    int g = idx / 40960;
    int r = idx % 40960;
    int kk = r / 4096;
    int r2 = r % 4096;
    int n  = r2 >> 9;
    int ln = (r2 >> 3) & 63;
    int i  = r2 & 7;
    int v = kk * 32 + (ln >> 4) * 8 + i;   // k index (codebook row)
    int d = n * 16 + (ln & 15);            // col index
    cbp[idx] = cvt_bf16(cb[((size_t)g * V_ + v) * D_ + d]);
    return;
  }
  idx -= N3;
  if (idx < GV) { avg_g[idx] = 0.f; return; }
  idx -= GV;
  if (idx == 0) *closs = 0.f;
}

// ---------------- kernel A: logits GEMM + gumbel softmax + avg_probs + probs@codebook ----------------
__global__ __launch_bounds__(512, 2) void pq_kA(
    const float* __restrict__ x, const float* __restrict__ b_in,
    const float* __restrict__ gum, const ushort_t* __restrict__ winb,
    const ushort_t* __restrict__ cbp, ushort_t* __restrict__ qmid,
    float* __restrict__ avg_g) {
  __shared__ char smem[84480];
  char* sA = smem;                         // stage A [128][32] bf16, 64B rows, swizzled
  char* sB = smem + 8192;                  // stage B [640][32] bf16, 64B rows, swizzled
  char* sP = smem;                         // probs  [64][640] bf16, 1280B rows, swizzled (union)
  float* sAvg = (float*)(smem + 81920);    // [640]

  const int tid = threadIdx.x;
  const int lane = tid & 63;
  const int wid = tid >> 6;    // 0..7
  const int wm = wid >> 1;     // 0..3  (M wave)
  const int g  = wid & 1;      // group
  const int lo = lane & 15;
  const int hi = lane >> 4;
  const int row0 = blockIdx.x * 128;

  for (int i = tid; i < GV; i += 512) sAvg[i] = 0.f;

  f32x4 acc[2][20];
#pragma unroll
  for (int m = 0; m < 2; ++m)
#pragma unroll
    for (int n = 0; n < 20; ++n) acc[m][n] = (f32x4){0.f, 0.f, 0.f, 0.f};

  __syncthreads();

  // ---- GEMM1: logits[128][640] = x_tile[128][1024] @ W_in^T ----
  for (int ks = 0; ks < 32; ++ks) {
    const int kb = ks * 32;
    // stage A: 128x32 f32 -> bf16
#pragma unroll
    for (int u = 0; u < 2; ++u) {
      int f = u * 512 + tid;
      int r = f >> 3, c4 = f & 7;
      const float4 xv = *reinterpret_cast<const float4*>(x + (size_t)(row0 + r) * H_ + kb + c4 * 4);
      uint2 w;
      w.x = (uint_t)cvt_bf16(xv.x) | ((uint_t)cvt_bf16(xv.y) << 16);
      w.y = (uint_t)cvt_bf16(xv.z) | ((uint_t)cvt_bf16(xv.w) << 16);
      int byte = (r * 64 + c4 * 8) ^ ((r & 7) << 4);
      *reinterpret_cast<uint2*>(sA + byte) = w;
    }
    // stage B: 640x32 bf16 copy
#pragma unroll
    for (int u = 0; u < 5; ++u) {
      int s = u * 512 + tid;
      int r = s >> 2, c = s & 3;
      const uint4 wv = *reinterpret_cast<const uint4*>(winb + (size_t)r * H_ + kb + c * 8);
      int byte = (r * 64 + c * 16) ^ ((r & 7) << 4);
      *reinterpret_cast<uint4*>(sB + byte) = wv;
    }
    __syncthreads();
    bf16x8 af[2];
#pragma unroll
    for (int m = 0; m < 2; ++m) {
      int row = wm * 32 + m * 16 + lo;
      int byte = (row * 64 + hi * 16) ^ ((row & 7) << 4);
      af[m] = *reinterpret_cast<const bf16x8*>(sA + byte);
    }
#pragma unroll
    for (int n = 0; n < 20; ++n) {
      int v = g * 320 + n * 16 + lo;
      int byte = (v * 64 + hi * 16) ^ ((v & 7) << 4);
      bf16x8 bf = *reinterpret_cast<const bf16x8*>(sB + byte);
      acc[0][n] = __builtin_amdgcn_mfma_f32_16x16x32_bf16(af[0], bf, acc[0][n], 0, 0, 0);
      acc[1][n] = __builtin_amdgcn_mfma_f32_16x16x32_bf16(af[1], bf, acc[1][n], 0, 0, 0);
    }
    __syncthreads();
  }

  // ---- epilogue: gumbel softmax (wave-local rows), avg_probs, GEMM2 ----
  float bias[20];
#pragma unroll
  for (int n = 0; n < 20; ++n) bias[n] = b_in[g * 320 + n * 16 + lo];

#pragma unroll
  for (int mrep = 0; mrep < 2; ++mrep) {
#pragma unroll
    for (int j = 0; j < 4; ++j) {
      const int trow = row0 + wm * 32 + mrep * 16 + hi * 4 + j;
      const float* up = gum + ((size_t)trow * G_ + g) * V_;
      float zmax = -3.0e38f;
#pragma unroll
      for (int n = 0; n < 20; ++n) {
        float u = up[n * 16 + lo];
        float gv = -__logf(-__logf(u));
        float z = acc[mrep][n][j] + bias[n] + gv;
        acc[mrep][n][j] = z;
        zmax = fmaxf(zmax, z);
      }
#pragma unroll
      for (int mk = 1; mk <= 8; mk <<= 1) zmax = fmaxf(zmax, __shfl_xor(zmax, mk));
      float s = 0.f;
#pragma unroll
      for (int n = 0; n < 20; ++n) {
        float p = __expf(acc[mrep][n][j] - zmax);
        acc[mrep][n][j] = p;
        s += p;
      }
#pragma unroll
      for (int mk = 1; mk <= 8; mk <<= 1) s += __shfl_xor(s, mk);
      float inv = 1.f / s;
#pragma unroll
      for (int n = 0; n < 20; ++n) acc[mrep][n][j] *= inv;
    }
    // avg_probs accumulation (sum over this wave's 16 rows)
#pragma unroll
    for (int n = 0; n < 20; ++n) {
      float cs = acc[mrep][n][0] + acc[mrep][n][1] + acc[mrep][n][2] + acc[mrep][n][3];
      cs += __shfl_xor(cs, 16);
      cs += __shfl_xor(cs, 32);
      if (hi == 0) atomicAdd(&sAvg[g * 320 + n * 16 + lo], cs);
    }
    // probs -> LDS bf16 (pair-packed, wave-local region)
#pragma unroll
    for (int n = 0; n < 20; ++n) {
#pragma unroll
      for (int j = 0; j < 4; ++j) {
        float v = acc[mrep][n][j];
        float pv = __shfl_xor(v, 1);
        if ((lane & 1) == 0) {
          uint_t w = (uint_t)cvt_bf16(v) | ((uint_t)cvt_bf16(pv) << 16);
          int prow = wm * 16 + hi * 4 + j;
          int byte = (prow * 1280 + (g * 320 + n * 16 + lo) * 2) ^ ((prow & 7) << 4);
          *reinterpret_cast<uint_t*>(sP + byte) = w;
        }
      }
    }
    asm volatile("s_waitcnt lgkmcnt(0)" ::: "memory");
    // GEMM2: qmid[16][128] = P[16][320] @ codebook[g]
    f32x4 acc2[8];
#pragma unroll
    for (int n = 0; n < 8; ++n) acc2[n] = (f32x4){0.f, 0.f, 0.f, 0.f};
#pragma unroll
    for (int kk = 0; kk < 10; ++kk) {
      int prow = wm * 16 + lo;
      int byte = (prow * 1280 + g * 640 + kk * 64 + hi * 16) ^ ((prow & 7) << 4);
      bf16x8 ap = *reinterpret_cast<const bf16x8*>(sP + byte);
#pragma unroll
      for (int n = 0; n < 8; ++n) {
        bf16x8 bc = *reinterpret_cast<const bf16x8*>(cbp + ((size_t)((g * 10 + kk) * 8 + n) * 64 + lane) * 8);
        acc2[n] = __builtin_amdgcn_mfma_f32_16x16x32_bf16(ap, bc, acc2[n], 0, 0, 0);
      }
    }
    // write qmid bf16 (pair-packed u32 stores)
#pragma unroll
    for (int n = 0; n < 8; ++n) {
#pragma unroll
      for (int j = 0; j < 4; ++j) {
        float v = acc2[n][j];
        float pv = __shfl_xor(v, 1);
        if ((lane & 1) == 0) {
          uint_t w = (uint_t)cvt_bf16(v) | ((uint_t)cvt_bf16(pv) << 16);
          int trow = row0 + wm * 32 + mrep * 16 + hi * 4 + j;
          *reinterpret_cast<uint_t*>(qmid + (size_t)trow * GD + g * 128 + n * 16 + lo) = w;
        }
      }
    }
  }
  __syncthreads();
  for (int i = tid; i < GV; i += 512) atomicAdd(&avg_g[i], sAvg[i]);
}

// ---------------- kernel B: q = qmid @ W_out^T + b_out, commit loss partial ----------------
__global__ __launch_bounds__(512, 2) void pq_kB(
    const ushort_t* __restrict__ qmid, const ushort_t* __restrict__ woutb,
    const float* __restrict__ b_out, const float* __restrict__ x,
    float* __restrict__ out, float* __restrict__ closs) {
  __shared__ char smem[49152 + 64];
  char* sA = smem;            // [128][64] bf16 swizzled
  char* sB = smem + 16384;    // [256][64] bf16 swizzled
  float* sRed = (float*)(smem + 49152);

  const int tid = threadIdx.x;
  const int lane = tid & 63;
  const int wid = tid >> 6;
  const int wm = wid >> 2;    // 0..1
  const int wn = wid & 3;     // 0..3
  const int lo = lane & 15, hi = lane >> 4;
  const int tm = blockIdx.x >> 2;
  const int tn = blockIdx.x & 3;
  const int row0 = tm * 128;
  const int col0 = tn * 256;

  f32x4 acc[4][4];
#pragma unroll
  for (int mr = 0; mr < 4; ++mr)
#pragma unroll
    for (int nr = 0; nr < 4; ++nr) acc[mr][nr] = (f32x4){0.f, 0.f, 0.f, 0.f};

  for (int ks = 0; ks < 4; ++ks) {
    const int kb = ks * 64;
#pragma unroll
    for (int u = 0; u < 2; ++u) {
      int s = u * 512 + tid;
      int r = s >> 3, c = s & 7;
      uint4 wv = *reinterpret_cast<const uint4*>(qmid + (size_t)(row0 + r) * GD + kb + c * 8);
      int byte = (r * 128 + c * 16) ^ ((r & 7) << 4);
      *reinterpret_cast<uint4*>(sA + byte) = wv;
    }
#pragma unroll
    for (int u = 0; u < 4; ++u) {
      int s = u * 512 + tid;
      int r = s >> 3, c = s & 7;
      uint4 wv = *reinterpret_cast<const uint4*>(woutb + (size_t)(col0 + r) * GD + kb + c * 8);
      int byte = (r * 128 + c * 16) ^ ((r & 7) << 4);
      *reinterpret_cast<uint4*>(sB + byte) = wv;
    }
    __syncthreads();
#pragma unroll
    for (int kk = 0; kk < 2; ++kk) {
      bf16x8 af[4], bf[4];
#pragma unroll
      for (int mr = 0; mr < 4; ++mr) {
        int row = wm * 64 + mr * 16 + lo;
        int byte = (row * 128 + kk * 64 + hi * 16) ^ ((row & 7) << 4);
        af[mr] = *reinterpret_cast<const bf16x8*>(sA + byte);
      }
#pragma unroll
      for (int nr = 0; nr < 4; ++nr) {
        int col = wn * 64 + nr * 16 + lo;
        int byte = (col * 128 + kk * 64 + hi * 16) ^ ((col & 7) << 4);
        bf[nr] = *reinterpret_cast<const bf16x8*>(sB + byte);
      }
#pragma unroll
      for (int mr = 0; mr < 4; ++mr)
#pragma unroll
        for (int nr = 0; nr < 4; ++nr)
          acc[mr][nr] = __builtin_amdgcn_mfma_f32_16x16x32_bf16(af[mr], bf[nr], acc[mr][nr], 0, 0, 0);
    }
    __syncthreads();
  }
  // epilogue: bias, store q, commit loss
  float bias[4];
#pragma unroll
  for (int nr = 0; nr < 4; ++nr) bias[nr] = b_out[col0 + wn * 64 + nr * 16 + lo];
  float csum = 0.f;
#pragma unroll
  for (int mr = 0; mr < 4; ++mr)
#pragma unroll
    for (int nr = 0; nr < 4; ++nr)
#pragma unroll
      for (int j = 0; j < 4; ++j) {
        int row = row0 + wm * 64 + mr * 16 + hi * 4 + j;
        int col = col0 + wn * 64 + nr * 16 + lo;
        float q = acc[mr][nr][j] + bias[nr];
        out[(size_t)row * H_ + col] = q;
        float d = x[(size_t)row * H_ + col] - q;
        csum += d * d;
      }
#pragma unroll
  for (int mk = 1; mk <= 32; mk <<= 1) csum += __shfl_xor(csum, mk);
  if (lane == 0) sRed[wid] = csum;
  __syncthreads();
  if (tid == 0) {
    float t = 0.f;
    for (int w = 0; w < 8; ++w) t += sRed[w];
    atomicAdd(closs, t);
  }
}

// ---------------- kernel C: finalize perplexity + commit loss ----------------
__global__ void pq_kC(const float* __restrict__ avg_g, const float* __restrict__ closs,
                      float* __restrict__ out) {
  const int lane = threadIdx.x;  // 64 threads, 1 wave
  float a0 = 0.f, a1 = 0.f;
  for (int v = lane; v < V_; v += 64) {
    float p0 = avg_g[v] * (1.f / (float)NT);
    a0 += p0 * __logf(p0 + 1e-9f);
    float p1 = avg_g[V_ + v] * (1.f / (float)NT);
    a1 += p1 * __logf(p1 + 1e-9f);
  }
#pragma unroll
  for (int mk = 1; mk <= 32; mk <<= 1) { a0 += __shfl_xor(a0, mk); a1 += __shfl_xor(a1, mk); }
  if (lane == 0) {
    out[(size_t)NT * H_]     = 0.5f * (__expf(-a0) + __expf(-a1));
    out[(size_t)NT * H_ + 1] = (*closs) * (1.f / ((float)NT * (float)H_));
  }
}

extern "C" void kernel_launch(void* const* d_in, const int* in_sizes, int n_in,
                              void* d_out, int out_size, void* d_ws, size_t ws_size,
                              hipStream_t stream) {
  const float* x     = (const float*)d_in[0];
  const float* W_in  = (const float*)d_in[1];
  const float* b_in  = (const float*)d_in[2];
  const float* cb    = (const float*)d_in[3];
  const float* W_out = (const float*)d_in[4];
  const float* b_out = (const float*)d_in[5];
  const float* gum   = (const float*)d_in[6];
  float* out = (float*)d_out;

  char* ws = (char*)d_ws;
  ushort_t* winb  = (ushort_t*)ws;                 // 640*1024*2   = 1,310,720 B
  ushort_t* woutb = (ushort_t*)(ws + 1310720);     // 1024*256*2   =   524,288 B
  ushort_t* cbp   = (ushort_t*)(ws + 1835008);     // 81920*2      =   163,840 B
  float*    avg_g = (float*)(ws + 1998848);        // 640*4        =     2,560 B
  float*    closs = (float*)(ws + 2001408);        // 16 B
  ushort_t* qmid  = (ushort_t*)(ws + 2001920);     // 32768*256*2  = 16,777,216 B

  pq_prep<<<3907, 256, 0, stream>>>(W_in, W_out, cb, winb, woutb, cbp, avg_g, closs);
  pq_kA<<<256, 512, 0, stream>>>(x, b_in, gum, winb, cbp, qmid, avg_g);
  pq_kB<<<1024, 512, 0, stream>>>(qmid, woutb, b_out, x, out, closs);
  pq_kC<<<1, 64, 0, stream>>>(avg_g, closs, out);
}